// Round 8
// baseline (197.066 us; speedup 1.0000x reference)
//
#include <hip/hip_runtime.h>

// DEC Student-t soft assignment, ALPHA=1 -> q_ij = 1/(1+d2_ij), row-normalized.
// d2 = ||h||^2 + ||c||^2 - 2 h.c ; cross term via bf16 MFMA, h_sq/c_sq exact fp32.
//
// R7 -> R8: ONE variable vs the verified R2 kernel. All 7 prior schedules pinned
// at 15-21% MfmaUtil regardless of K-loop structure -> the shared suspect is the
// C-WRITE pattern (per-lane 64-B granules at 4000-B row stride, partial L2
// lines, store-drain with ~2 blocks/CU). R8 keeps R2's K-loop verbatim and
// replaces only the epilogue: C-tile bounced through LDS (reuses the 32 KB
// staging buffer) and stored as fully-coalesced, 16B-aligned float4 runs
// (512 B contiguous per 32 lanes). K_CENT mask falls on a float4 boundary.

typedef unsigned short u16;
typedef __attribute__((ext_vector_type(8))) short bf16x8;  // 8 bf16 = 4 VGPRs
typedef __attribute__((ext_vector_type(4))) float f32x4;

#define N_ROWS 32768
#define K_CENT 1000
#define KP     1024   // padded centroid count
#define DDIM   1024

__device__ __forceinline__ u16 f2bf(float x) {
  unsigned u = __float_as_uint(x);
  u += 0x7fffu + ((u >> 16) & 1u);   // round-to-nearest-even
  return (u16)(u >> 16);
}

// async global->LDS, 16 B per lane. LDS dest is wave-uniform base; HW adds lane*16.
__device__ __forceinline__ void gload_lds16(const u16* g, u16* s) {
  __builtin_amdgcn_global_load_lds((__attribute__((address_space(1))) void*)g,
                                   (__attribute__((address_space(3))) void*)s,
                                   16, 0, 0);
}

// ---------------- prep kernels ----------------

__global__ __launch_bounds__(256) void prep_h(const float* __restrict__ h,
                                              u16* __restrict__ hb,
                                              float* __restrict__ hsq,
                                              float* __restrict__ rowsum) {
  const int row = blockIdx.x;
  const int t = threadIdx.x;
  const float4 v = reinterpret_cast<const float4*>(h + (size_t)row * DDIM)[t];
  ushort4 b;
  b.x = f2bf(v.x); b.y = f2bf(v.y); b.z = f2bf(v.z); b.w = f2bf(v.w);
  reinterpret_cast<ushort4*>(hb + (size_t)row * DDIM)[t] = b;
  float ss = v.x * v.x + v.y * v.y + v.z * v.z + v.w * v.w;
#pragma unroll
  for (int m = 1; m < 64; m <<= 1) ss += __shfl_xor(ss, m);
  __shared__ float sbuf[4];
  if ((t & 63) == 0) sbuf[t >> 6] = ss;
  __syncthreads();
  if (t == 0) {
    hsq[row] = sbuf[0] + sbuf[1] + sbuf[2] + sbuf[3];
    rowsum[row] = 0.0f;
  }
}

__global__ __launch_bounds__(256) void prep_c(const float* __restrict__ c,
                                              u16* __restrict__ cb,
                                              float* __restrict__ csq) {
  const int row = blockIdx.x;
  const int t = threadIdx.x;
  if (row < K_CENT) {
    const float4 v = reinterpret_cast<const float4*>(c + (size_t)row * DDIM)[t];
    ushort4 b;
    b.x = f2bf(v.x); b.y = f2bf(v.y); b.z = f2bf(v.z); b.w = f2bf(v.w);
    reinterpret_cast<ushort4*>(cb + (size_t)row * DDIM)[t] = b;
    float ss = v.x * v.x + v.y * v.y + v.z * v.z + v.w * v.w;
#pragma unroll
    for (int m = 1; m < 64; m <<= 1) ss += __shfl_xor(ss, m);
    __shared__ float sbuf[4];
    if ((t & 63) == 0) sbuf[t >> 6] = ss;
    __syncthreads();
    if (t == 0) csq[row] = sbuf[0] + sbuf[1] + sbuf[2] + sbuf[3];
  } else {
    ushort4 z; z.x = z.y = z.z = z.w = 0;
    reinterpret_cast<ushort4*>(cb + (size_t)row * DDIM)[t] = z;
    if (t == 0) csq[row] = 1e30f;  // pad rows: q ~ 1/(1+1e30) ~ 0
  }
}

// ---------------- main GEMM + q epilogue ----------------
// Tile = 128 rows x 32 k bf16 = 512 granules of 16 B. Logical granule
// g = 4*row + hi, stored at p = g ^ ((g>>3)&7) (involution; 0 bank conflicts
// verified R2-R6). global_load_lds writes linearly; global source pre-permuted.

__device__ __forceinline__ void stage_tile(const u16* __restrict__ gA,
                                           const u16* __restrict__ gB,
                                           u16* sA, u16* sB,
                                           int w, int l, int k0) {
#pragma unroll
  for (int i = 0; i < 2; ++i) {
    const int c = w + i * 4;
    const int p = c * 64 + l;            // linear granule this lane writes
    const int g = p ^ ((p >> 3) & 7);    // logical granule whose data belongs at p
    const int roff = g >> 2;
    const int koff = (g & 3) * 8;
    const size_t go = (size_t)roff * DDIM + k0 + koff;
    gload_lds16(gA + go, sA + c * 512);
    gload_lds16(gB + go, sB + c * 512);
  }
}

__global__ __launch_bounds__(256) void gemm_q(const u16* __restrict__ hb,
                                              const u16* __restrict__ cb,
                                              const float* __restrict__ hsq,
                                              const float* __restrict__ csq,
                                              float* __restrict__ out,
                                              float* __restrict__ rowsum) {
  __shared__ char SMEM[32768];
  u16* As0 = (u16*)SMEM;               // 8 KB each
  u16* As1 = (u16*)(SMEM + 8192);
  u16* Bs0 = (u16*)(SMEM + 16384);
  u16* Bs1 = (u16*)(SMEM + 24576);
  float* bounce = (float*)SMEM;        // epilogue alias: 64 x 128 f32 = 32 KB

  const int bid = blockIdx.x;
  // XCD swizzle (2048 % 8 == 0): each XCD gets 32 consecutive row panels x 8 col blocks
  const int swz = ((bid & 7) << 8) | (bid >> 3);
  const int bcol = swz & 7;    // 8 column blocks of 128 (KP=1024)
  const int brow = swz >> 3;   // 256 row panels of 128

  const int t = threadIdx.x;
  const int w = t >> 6;
  const int l = t & 63;
  const int wr = w >> 1;       // wave row (0..1), 64 rows each
  const int wc = w & 1;        // wave col (0..1), 64 cols each

  const u16* gA = hb + (size_t)brow * 128 * DDIM;
  const u16* gB = cb + (size_t)bcol * 128 * DDIM;

  f32x4 acc[4][4] = {};

  stage_tile(gA, gB, As0, Bs0, w, l, 0);

  const int hi = l >> 4;
  const int rA0 = wr * 64 + (l & 15);
  const int rB0 = wc * 64 + (l & 15);

  const int NT = DDIM / 32;
  for (int kt = 0; kt < NT; ++kt) {
    const int cur = kt & 1;
    __syncthreads();  // stage(kt) complete (vmcnt drain) + prior reads done
    if (kt + 1 < NT)
      stage_tile(gA, gB, cur ? As0 : As1, cur ? Bs0 : Bs1, w, l, (kt + 1) * 32);

    const u16* SA = cur ? As1 : As0;
    const u16* SB = cur ? Bs1 : Bs0;
    bf16x8 aF[4], bF[4];
#pragma unroll
    for (int m = 0; m < 4; ++m) {
      const int ga = ((rA0 + m * 16) << 2) | hi;
      const int gb = ((rB0 + m * 16) << 2) | hi;
      aF[m] = *(const bf16x8*)&SA[(ga ^ ((ga >> 3) & 7)) << 3];
      bF[m] = *(const bf16x8*)&SB[(gb ^ ((gb >> 3) & 7)) << 3];
    }
#pragma unroll
    for (int m = 0; m < 4; ++m)
#pragma unroll
      for (int n = 0; n < 4; ++n)
        acc[m][n] = __builtin_amdgcn_mfma_f32_16x16x32_bf16(aF[m], bF[n], acc[m][n], 0, 0, 0);
  }

  // ---- epilogue: q in-place, rowsum atomics, then COALESCED store via LDS ----
  // C/D layout (16x16x32): col = l&15, row = (l>>4)*4 + reg
  const int lr = (l >> 4) << 2;
  const int lc = l & 15;
  const int gi0 = brow * 128 + wr * 64;

#pragma unroll
  for (int m = 0; m < 4; ++m) {
    float hs[4];
#pragma unroll
    for (int r = 0; r < 4; ++r) hs[r] = hsq[gi0 + m * 16 + lr + r];
    float rs[4] = {0.f, 0.f, 0.f, 0.f};
#pragma unroll
    for (int n = 0; n < 4; ++n) {
      const float cs = csq[bcol * 128 + wc * 64 + n * 16 + lc];
#pragma unroll
      for (int r = 0; r < 4; ++r) {
        float d2 = hs[r] + cs - 2.0f * acc[m][n][r];
        d2 = fmaxf(d2, 0.0f);
        const float qv = 1.0f / (1.0f + d2);
        acc[m][n][r] = qv;           // keep for the bounce store
        rs[r] += qv;
      }
    }
#pragma unroll
    for (int r = 0; r < 4; ++r) {
      float v = rs[r];
      v += __shfl_xor(v, 1);
      v += __shfl_xor(v, 2);
      v += __shfl_xor(v, 4);
      v += __shfl_xor(v, 8);
      if (lc == 0) atomicAdd(&rowsum[gi0 + m * 16 + lr + r], v);
    }
  }

  // Two 64-row chunks; each: owning waves (wr==c) scatter frags into LDS,
  // then ALL 256 threads store 512-B-contiguous float4 runs.
  __syncthreads();   // all waves done with staging-LDS reads
#pragma unroll
  for (int c = 0; c < 2; ++c) {
    if (wr == c) {
#pragma unroll
      for (int m = 0; m < 4; ++m)
#pragma unroll
        for (int n = 0; n < 4; ++n)
#pragma unroll
          for (int r = 0; r < 4; ++r)
            bounce[(m * 16 + lr + r) * 128 + wc * 64 + n * 16 + lc] = acc[m][n][r];
    }
    __syncthreads();
    const int rloc = t >> 5;          // 0..7
    const int cg   = t & 31;          // col group of 4 floats
    const int gcol = bcol * 128 + cg * 4;
    if (gcol < K_CENT) {              // mask lands exactly on a float4 boundary
#pragma unroll
      for (int it = 0; it < 8; ++it) {
        const int rr = rloc + it * 8;
        *(float4*)(out + (size_t)(brow * 128 + c * 64 + rr) * K_CENT + gcol) =
            *(const float4*)&bounce[rr * 128 + cg * 4];
      }
    }
    __syncthreads();
  }
}

// ---------------- normalization ----------------

__global__ __launch_bounds__(256) void norm_k(float* __restrict__ out,
                                              const float* __restrict__ rowsum) {
  const int row = blockIdx.x;
  const int t = threadIdx.x;
  if (t < 250) {  // 1000 floats = 250 float4 per row (4000 B, 16B-aligned)
    const float inv = 1.0f / rowsum[row];
    float4* p = reinterpret_cast<float4*>(out) + (size_t)row * 250 + t;
    float4 v = *p;
    v.x *= inv; v.y *= inv; v.z *= inv; v.w *= inv;
    *p = v;
  }
}

// ---------------- launch ----------------

extern "C" void kernel_launch(void* const* d_in, const int* in_sizes, int n_in,
                              void* d_out, int out_size, void* d_ws, size_t ws_size,
                              hipStream_t stream) {
  const float* h   = (const float*)d_in[0];
  const float* cen = (const float*)d_in[1];
  float* out = (float*)d_out;
  char* ws = (char*)d_ws;

  u16*   cb     = (u16*)(ws);                           // 2 MB
  u16*   hb     = (u16*)(ws + 2097152);                 // 64 MB
  float* hsq    = (float*)(ws + 2097152 + 67108864);    // 128 KB
  float* csq    = (float*)(ws + 2097152 + 67108864 + 131072);   // 4 KB
  float* rowsum = (float*)(ws + 2097152 + 67108864 + 131072 + 4096); // 128 KB

  prep_c<<<KP, 256, 0, stream>>>(cen, cb, csq);
  prep_h<<<N_ROWS, 256, 0, stream>>>(h, hb, hsq, rowsum);
  gemm_q<<<(N_ROWS / 128) * (KP / 128), 256, 0, stream>>>(hb, cb, hsq, csq, out, rowsum);
  norm_k<<<N_ROWS, 256, 0, stream>>>(out, rowsum);
}